// Round 6
// baseline (552.915 us; speedup 1.0000x reference)
//
#include <hip/hip_runtime.h>
#include <hip/hip_bf16.h>
#include <math.h>

#define N_NODES 50000
#define N_EDGES 800000
#define HID 128
#define NGRAPH 256
#define NLAYER 2

typedef __bf16 bf16x8 __attribute__((ext_vector_type(8)));
typedef float f32x4 __attribute__((ext_vector_type(4)));

__device__ __forceinline__ float gelu_f(float v) {
    return 0.5f * v * (1.0f + erff(v * 0.70710678118654752f));
}

// ---------------- CSR build ----------------
__global__ void hist_kernel(const int* __restrict__ tgt, int* __restrict__ deg) {
    int e = blockIdx.x * 256 + threadIdx.x;
    if (e < N_EDGES) atomicAdd(&deg[tgt[e]], 1);
}

__global__ void scan_a(const int* __restrict__ deg, int* __restrict__ offp,
                       int* __restrict__ bsum, int n) {
    __shared__ int s[256];
    int tid = threadIdx.x;
    int i = blockIdx.x * 256 + tid;
    int v = (i < n) ? deg[i] : 0;
    s[tid] = v;
    __syncthreads();
    for (int d = 1; d < 256; d <<= 1) {
        int t = (tid >= d) ? s[tid - d] : 0;
        __syncthreads();
        s[tid] += t;
        __syncthreads();
    }
    if (i < n) offp[i] = s[tid] - v;
    if (tid == 255) bsum[blockIdx.x] = s[255];
}

__global__ void scan_b(int* __restrict__ bsum, int nb) {
    __shared__ int s[256];
    int tid = threadIdx.x;
    int v = (tid < nb) ? bsum[tid] : 0;
    s[tid] = v;
    __syncthreads();
    for (int d = 1; d < 256; d <<= 1) {
        int t = (tid >= d) ? s[tid - d] : 0;
        __syncthreads();
        s[tid] += t;
        __syncthreads();
    }
    bsum[tid] = s[tid] - v;
}

__global__ void scan_c(const int* __restrict__ offp, const int* __restrict__ bsum,
                       int* __restrict__ offs, int* __restrict__ cur, int n, int e_total) {
    int i = blockIdx.x * 256 + threadIdx.x;
    if (i < n) {
        int o = offp[i] + bsum[blockIdx.x];
        offs[i] = o;
        cur[i] = o;
    }
    if (i == 0) offs[n] = e_total;
}

// scatter: CSR-position -> packed {src, dd*16+pp}
__global__ void scatter_kernel(const int* __restrict__ tgt, const int* __restrict__ src,
                               const int* __restrict__ sd, const int* __restrict__ sp,
                               int* __restrict__ cur, int2* __restrict__ ei2) {
    int e = blockIdx.x * 256 + threadIdx.x;
    if (e < N_EDGES) {
        int pos = atomicAdd(&cur[tgt[e]], 1);
        ei2[pos] = make_int2(src[e], (sd[e] << 4) | sp[e]);
    }
}

// ---------------- node encoder ----------------
__global__ void encoder_kernel(const int* __restrict__ attr, const float* __restrict__ emb,
                               float* __restrict__ x, __bf16* __restrict__ xb) {
    int idx = blockIdx.x * 256 + threadIdx.x;  // N*128
    int n = idx >> 7, c = idx & 127;
    const int4 a = *(const int4*)(attr + n * 4);
    float s = emb[(0 * 64 + a.x) * 128 + c] + emb[(1 * 64 + a.y) * 128 + c] +
              emb[(2 * 64 + a.z) * 128 + c] + emb[(3 * 64 + a.w) * 128 + c];
    x[idx] = s;
    xb[idx] = (__bf16)s;
}

// ---------------- weight repack: fp32 [CI][CO] -> bf16 fragment units ----------------
// unit (kg, C0+u) holds src col C0 + sigma(u), rows kg*8..kg*8+7.
// sigma(u) = (u&15)*8 + (u>>4) per 128-col block: each lane's 8 C-cols are
// contiguous true cols -> vectorized epilogues, channel-natural buffers.
__global__ void repack_kernel(const float* __restrict__ Wq, const float* __restrict__ Wk,
                              const float* __restrict__ Wv, const float* __restrict__ Wa,
                              const float* __restrict__ Wmid, const float* __restrict__ Wo,
                              __bf16* wqkvf, __bf16* waf, __bf16* wmidf, __bf16* wof) {
    int u = blockIdx.x * 256 + threadIdx.x;  // 0..32767
    int l = u >> 14, r = u & 16383;
    const float* srcp;
    __bf16* dstp;
    int kg, scol, srcCO;
    if (r < 6144) {  // fused QKV, CO=384
        kg = r / 384;
        int uu = r % 384;
        int sec = uu >> 7, cc = uu & 127;
        scol = ((cc & 15) << 3) | (cc >> 4);
        const float* Ws = (sec == 0) ? Wq : (sec == 1) ? Wk : Wv;
        srcp = Ws + l * 16384;
        srcCO = 128;
        dstp = wqkvf + (size_t)l * 49152 + (size_t)r * 8;
    } else if (r < 8192) {  // Wa
        int rr = r - 6144;
        kg = rr >> 7;
        int cc = rr & 127;
        scol = ((cc & 15) << 3) | (cc >> 4);
        srcp = Wa + l * 16384;
        srcCO = 128;
        dstp = waf + (size_t)l * 16384 + (size_t)rr * 8;
    } else if (r < 12288) {  // Wmid, CO=256
        int rr = r - 8192;
        kg = rr >> 8;
        int uu = rr & 255;
        int blk = uu >> 7, cc = uu & 127;
        scol = blk * 128 + (((cc & 15) << 3) | (cc >> 4));
        srcp = Wmid + l * 32768;
        srcCO = 256;
        dstp = wmidf + (size_t)l * 32768 + (size_t)rr * 8;
    } else {  // Wo, CI=256
        int rr = r - 12288;
        kg = rr >> 7;  // 0..31
        int cc = rr & 127;
        scol = ((cc & 15) << 3) | (cc >> 4);
        srcp = Wo + l * 32768;
        srcCO = 128;
        dstp = wof + (size_t)l * 32768 + (size_t)rr * 8;
    }
    bf16x8 o;
#pragma unroll
    for (int j = 0; j < 8; j++) o[j] = (__bf16)srcp[(kg * 8 + j) * srcCO + scol];
    *(bf16x8*)dstp = o;
}

// ---------------- combined relational tables, both layers, direct from fp32 ----
// tkv[l][md][c]: c<128 -> (de[dd]+pe[pp]) @ Wk col c ; c>=128 -> @ Wv col (c-128)
__global__ void tkv_kernel(const float* __restrict__ de, const float* __restrict__ pe,
                           const float* __restrict__ Wk, const float* __restrict__ Wv,
                           __bf16* __restrict__ tkv) {
    int l = blockIdx.x >> 9;   // 0..1
    int md = blockIdx.x & 511;
    int dd = md >> 4, pp = md & 15;
    int c = threadIdx.x;       // 0..255
    __shared__ float sde[128];
    if (c < 128) sde[c] = de[l * 4096 + dd * 128 + c] + pe[l * 2048 + pp * 128 + c];
    __syncthreads();
    const float* W = (c < 128) ? (Wk + l * 16384) : (Wv + l * 16384);
    int cc = c & 127;
    float acc = 0.f;
#pragma unroll 4
    for (int k = 0; k < 128; k++) acc = fmaf(sde[k], W[k * 128 + cc], acc);
    tkv[(size_t)blockIdx.x * 256 + c] = (__bf16)acc;
}

// ---------------- small setup: per-graph invc + out init, fused QKV bias ----
__global__ void setup_small(const int* __restrict__ batch, const float* __restrict__ bout,
                            const float* __restrict__ bq, const float* __restrict__ bk,
                            const float* __restrict__ bv,
                            float* __restrict__ invc, float* __restrict__ outp,
                            float* __restrict__ bqkv) {
    if (blockIdx.x == 0) {
        int g = threadIdx.x;  // 256 graphs
        int lo = 0, hi = N_NODES;
        while (lo < hi) { int mid = (lo + hi) >> 1; if (batch[mid] < g) lo = mid + 1; else hi = mid; }
        int start = lo;
        lo = start; hi = N_NODES;
        while (lo < hi) { int mid = (lo + hi) >> 1; if (batch[mid] < g + 1) lo = mid + 1; else hi = mid; }
        int cnt = lo - start;
        invc[g] = 1.0f / fmaxf((float)cnt, 1.0f);
        outp[g] = bout[0];
    } else {
        int r = (blockIdx.x - 1) * 256 + threadIdx.x;  // 0..767
        int l = r / 384, c = r % 384;
        float v = (c < 128) ? bq[l * 128 + c]
                : (c < 256) ? bk[l * 128 + c - 128]
                            : bv[l * 128 + c - 256];
        bqkv[r] = v;
    }
}

// ---------------- MFMA GEMM: wave tile 16 rows x 128 cols, block 4 waves = 64 rows ----
// grid (CO/128, ceil(M/64)). Optional fused: residual, LayerNorm, gelu-out, pooled
// readout. POOL: per-block LDS per-graph accumulation, ~2 global atomics/block.
template <int CI, bool GOUT, bool LN, bool POOL>
__global__ __launch_bounds__(256) void mfma_gemm(
    const __bf16* __restrict__ A, const __bf16* __restrict__ Wf,
    const float* __restrict__ bias, const float* __restrict__ res,
    const float* __restrict__ lng, const float* __restrict__ lnb,
    float* outf, __bf16* outb,
    const int* __restrict__ batch, const float* __restrict__ invc,
    const float* __restrict__ WoutV, float* __restrict__ outp,
    int M, int CO) {
    __shared__ float ps[POOL ? NGRAPH : 1];
    int lane = threadIdx.x & 63;
    int wv = threadIdx.x >> 6;
    int row0 = blockIdx.y * 64 + wv * 16;
    int col0 = blockIdx.x * 128;
    bool active = row0 < M;
    if (POOL) {
        ps[threadIdx.x] = 0.f;
        __syncthreads();
    } else if (!active) {
        return;
    }
    int quad = lane >> 4, tq = lane & 15;
    if (active) {
        f32x4 acc[8] = {};
#pragma unroll
        for (int k0 = 0; k0 < CI; k0 += 32) {
            int rr = row0 + tq;
            if (rr >= M) rr = M - 1;
            bf16x8 af = *(const bf16x8*)(A + (size_t)rr * CI + k0 + quad * 8);
#pragma unroll
            for (int nt = 0; nt < 8; nt++) {
                bf16x8 bfr = *(const bf16x8*)(Wf + ((size_t)((k0 >> 3) + quad) * CO + col0 + nt * 16 + tq) * 8);
                acc[nt] = __builtin_amdgcn_mfma_f32_16x16x32_bf16(af, bfr, acc[nt], 0, 0, 0);
            }
        }
        // epilogue: lane's true cols are col0 + tq*8 .. +7 (sigma repack)
        int cb = col0 + tq * 8;
        float bia[8] = {};
        if (bias) {
            float4 b0 = *(const float4*)(bias + cb);
            float4 b1 = *(const float4*)(bias + cb + 4);
            bia[0] = b0.x; bia[1] = b0.y; bia[2] = b0.z; bia[3] = b0.w;
            bia[4] = b1.x; bia[5] = b1.y; bia[6] = b1.z; bia[7] = b1.w;
        }
        float gv[8], bv2[8];
        if (LN) {
#pragma unroll
            for (int t = 0; t < 8; t++) { gv[t] = lng[cb + t]; bv2[t] = lnb[cb + t]; }
        }
        float wo8[8];
        if (POOL) {
#pragma unroll
            for (int t = 0; t < 8; t++) wo8[t] = WoutV[cb + t];
        }
#pragma unroll
        for (int v = 0; v < 4; v++) {
            int rr = row0 + quad * 4 + v;
            if (rr >= M) continue;
            float val[8];
#pragma unroll
            for (int nt = 0; nt < 8; nt++) val[nt] = acc[nt][v] + bia[nt];
            if (res) {  // residual (CO==128 only)
                float4 r0 = *(const float4*)(res + (size_t)rr * 128 + tq * 8);
                float4 r1 = *(const float4*)(res + (size_t)rr * 128 + tq * 8 + 4);
                val[0] += r0.x; val[1] += r0.y; val[2] += r0.z; val[3] += r0.w;
                val[4] += r1.x; val[5] += r1.y; val[6] += r1.z; val[7] += r1.w;
            }
            if (GOUT) {
#pragma unroll
                for (int t = 0; t < 8; t++) val[t] = gelu_f(val[t]);
            }
            if (LN) {
                float s = 0.f, s2 = 0.f;
#pragma unroll
                for (int t = 0; t < 8; t++) { s += val[t]; s2 = fmaf(val[t], val[t], s2); }
#pragma unroll
                for (int o = 1; o < 16; o <<= 1) {
                    s += __shfl_xor(s, o);
                    s2 += __shfl_xor(s2, o);
                }
                float m = s * (1.0f / 128.0f);
                float var = s2 * (1.0f / 128.0f) - m * m;
                float rs = rsqrtf(var + 1e-5f);
#pragma unroll
                for (int t = 0; t < 8; t++) val[t] = (val[t] - m) * rs * gv[t] + bv2[t];
            }
            if (outf) {
                *(float4*)(outf + (size_t)rr * CO + cb) = make_float4(val[0], val[1], val[2], val[3]);
                *(float4*)(outf + (size_t)rr * CO + cb + 4) = make_float4(val[4], val[5], val[6], val[7]);
            }
            if (outb) {
                bf16x8 ov;
#pragma unroll
                for (int t = 0; t < 8; t++) ov[t] = (__bf16)val[t];
                *(bf16x8*)(outb + (size_t)rr * CO + cb) = ov;
            }
            if (POOL) {
                float dot = 0.f;
#pragma unroll
                for (int t = 0; t < 8; t++) dot = fmaf(val[t], wo8[t], dot);
#pragma unroll
                for (int o = 1; o < 16; o <<= 1) dot += __shfl_xor(dot, o);
                if (tq == 0) {
                    int g = batch[rr];
                    atomicAdd(&ps[g], dot * invc[g]);  // LDS atomic: fast, per-CU
                }
            }
        }
    }
    if (POOL) {
        __syncthreads();
        float pv = ps[threadIdx.x];
        if (pv != 0.f) atomicAdd(&outp[threadIdx.x], pv);
    }
}

// ---------------- attention: 4 nodes per wave, 8 edges in flight, 1 head/lane ----
// Block count 12500 -> 3125: round-5 counters (dur pinned ~73us across VALU diets,
// Occupancy 36%, HBM 34%) indicate launch/concurrency-bound, not VALU-bound.
__global__ __launch_bounds__(256) void attn_kernel(
    const __bf16* __restrict__ QKV, const __bf16* __restrict__ tkv,
    const int* __restrict__ offs, const int2* __restrict__ ei2,
    __bf16* __restrict__ outb) {
    int wv = threadIdx.x >> 6;
    int lane = threadIdx.x & 63;
    int slot = lane >> 3, h = lane & 7;
    int ch0 = h * 16;
    int i0 = blockIdx.x * 16 + wv * 4;
#pragma unroll 1
    for (int ii = 0; ii < 4; ii++) {
        int i = i0 + ii;
        if (i >= N_NODES) return;
        const __bf16* qp = QKV + (size_t)i * 384 + ch0;
        bf16x8 q0 = *(const bf16x8*)qp;
        bf16x8 q1 = *(const bf16x8*)(qp + 8);
        float qf[16];
#pragma unroll
        for (int t = 0; t < 8; t++) { qf[t] = (float)q0[t]; qf[8 + t] = (float)q1[t]; }
        int p0 = offs[i], p1 = offs[i + 1];
        float l = 0.f;
        float a[16] = {};
        int p = p0 + slot;
        int2 md = make_int2(0, 0);
        if (p < p1) md = ei2[p];
        while (p < p1) {
            int pn = p + 8;
            int2 mdn = md;
            if (pn < p1) mdn = ei2[pn];  // prefetch next metadata
            const __bf16* kr = QKV + (size_t)md.x * 384 + 128 + ch0;
            const __bf16* tr = tkv + md.y * 256 + ch0;
            bf16x8 k0 = *(const bf16x8*)kr;
            bf16x8 k1 = *(const bf16x8*)(kr + 8);
            bf16x8 v0 = *(const bf16x8*)(kr + 128);
            bf16x8 v1 = *(const bf16x8*)(kr + 136);
            bf16x8 t0 = *(const bf16x8*)tr;
            bf16x8 t1 = *(const bf16x8*)(tr + 8);
            bf16x8 u0 = *(const bf16x8*)(tr + 128);
            bf16x8 u1 = *(const bf16x8*)(tr + 136);
            float s = 0.f;
#pragma unroll
            for (int t = 0; t < 8; t++) {
                s = fmaf(qf[t], (float)k0[t] + (float)t0[t], s);
                s = fmaf(qf[8 + t], (float)k1[t] + (float)t1[t], s);
            }
            float pe = __expf(s * 0.25f);  // 1/sqrt(DK)
            l += pe;
#pragma unroll
            for (int t = 0; t < 8; t++) {
                a[t] = fmaf(pe, (float)v0[t] + (float)u0[t], a[t]);
                a[8 + t] = fmaf(pe, (float)v1[t] + (float)u1[t], a[8 + t]);
            }
            md = mdn;
            p = pn;
        }
        // merge the 8 edge slots (same head h at lane^{8,16,32})
#pragma unroll
        for (int off = 8; off <= 32; off <<= 1) {
            l += __shfl_xor(l, off);
#pragma unroll
            for (int t = 0; t < 16; t++) a[t] += __shfl_xor(a[t], off);
        }
        if (slot == 0) {
            float inv = 1.0f / (l + 1e-16f);
            bf16x8 o0, o1;
#pragma unroll
            for (int t = 0; t < 8; t++) {
                o0[t] = (__bf16)gelu_f(a[t] * inv);
                o1[t] = (__bf16)gelu_f(a[8 + t] * inv);
            }
            __bf16* op = outb + (size_t)i * 128 + ch0;
            *(bf16x8*)op = o0;
            *(bf16x8*)(op + 8) = o1;
        }
    }
}

extern "C" void kernel_launch(void* const* d_in, const int* in_sizes, int n_in,
                              void* d_out, int out_size, void* d_ws, size_t ws_size,
                              hipStream_t stream) {
    const int N = N_NODES, E = N_EDGES;
    const int* node_attr = (const int*)d_in[0];
    const int* batch_idx = (const int*)d_in[1];
    const int* edge_index = (const int*)d_in[2];
    const int* strat_dist = (const int*)d_in[3];
    const int* strat_path = (const int*)d_in[4];
    const float* atom_emb = (const float*)d_in[5];
    const float* dist_emb = (const float*)d_in[6];
    const float* path_emb = (const float*)d_in[7];
    const float* Wq = (const float*)d_in[8];
    const float* bq = (const float*)d_in[9];
    const float* Wk = (const float*)d_in[10];
    const float* bk = (const float*)d_in[11];
    const float* Wv = (const float*)d_in[12];
    const float* bv = (const float*)d_in[13];
    const float* Wa = (const float*)d_in[14];
    const float* ba = (const float*)d_in[15];
    const float* ln1g = (const float*)d_in[16];
    const float* ln1b = (const float*)d_in[17];
    const float* Wmid = (const float*)d_in[18];
    const float* bmid = (const float*)d_in[19];
    const float* Wo = (const float*)d_in[20];
    const float* bo = (const float*)d_in[21];
    const float* ln2g = (const float*)d_in[22];
    const float* ln2b = (const float*)d_in[23];
    const float* Wout = (const float*)d_in[24];
    const float* bout = (const float*)d_in[25];
    float* out = (float*)d_out;

    const int* src = edge_index;
    const int* tgt = edge_index + E;

    // ---- workspace layout ----
    size_t NF = (size_t)N * HID;          // 6.4e6
    float* x = (float*)d_ws;              // NF f32
    float* h = x + NF;                    // NF f32
    float* invc = h + NF;                 // 256
    float* bqkv = invc + 256;             // 768
    int2* ei2 = (int2*)(bqkv + 768);      // E
    __bf16* xb = (__bf16*)(ei2 + E);      // NF
    __bf16* QKVb = xb + NF;               // 3*NF (N x 384)
    __bf16* ab = QKVb + 3 * NF;           // NF
    __bf16* midb = ab + NF;               // 2*NF (N x 256)
    __bf16* tkv = midb + 2 * NF;          // 2 * 512*256
    __bf16* wqkvf = tkv + 262144;         // 2*49152
    __bf16* waf = wqkvf + 98304;          // 2*16384
    __bf16* wmidf = waf + 32768;          // 2*32768
    __bf16* wof = wmidf + 65536;          // 2*32768
    int* deg = (int*)(wof + 65536);       // N
    int* offp = deg + N;                  // N
    int* offs = offp + N;                 // N+1
    int* cur = offs + N + 1;              // N
    int* bsum = cur + N;                  // 256

    const int SB = 196;  // ceil(N/256)

    // ---- CSR build + repacks ----
    hipMemsetAsync(deg, 0, N * sizeof(int), stream);
    hist_kernel<<<E / 256, 256, 0, stream>>>(tgt, deg);
    scan_a<<<SB, 256, 0, stream>>>(deg, offp, bsum, N);
    scan_b<<<1, 256, 0, stream>>>(bsum, SB);
    scan_c<<<SB, 256, 0, stream>>>(offp, bsum, offs, cur, N, E);
    scatter_kernel<<<E / 256, 256, 0, stream>>>(tgt, src, strat_dist, strat_path, cur, ei2);
    repack_kernel<<<128, 256, 0, stream>>>(Wq, Wk, Wv, Wa, Wmid, Wo, wqkvf, waf, wmidf, wof);
    setup_small<<<4, 256, 0, stream>>>(batch_idx, bout, bq, bk, bv, invc, out, bqkv);
    tkv_kernel<<<1024, 256, 0, stream>>>(dist_emb, path_emb, Wk, Wv, tkv);
    encoder_kernel<<<(N * HID) / 256, 256, 0, stream>>>(node_attr, atom_emb, x, xb);

    const int GB = (N + 63) / 64;   // 782 row-blocks
    const int AB = (N + 15) / 16;   // 3125 attn blocks (4 nodes/wave)

    for (int l = 0; l < NLAYER; ++l) {
        // fused QKV (bias folded) -> N x 384 bf16, channel-natural
        mfma_gemm<128, false, false, false><<<dim3(3, GB), 256, 0, stream>>>(
            xb, wqkvf + l * 49152, bqkv + l * 384, nullptr, nullptr, nullptr,
            nullptr, QKVb, nullptr, nullptr, nullptr, nullptr, N, 384);

        // segment-softmax attention; writes gelu(aggr) bf16 into ab
        attn_kernel<<<AB, 256, 0, stream>>>(QKVb, tkv + l * 131072, offs, ei2, ab);

        // h = LN1(gelu(aggr)@Wa + ba + x) -> h fp32 + ab bf16 (in-place)
        mfma_gemm<128, false, true, false><<<dim3(1, GB), 256, 0, stream>>>(
            ab, waf + l * 16384, ba + l * 128, x, ln1g + l * 128, ln1b + l * 128,
            h, ab, nullptr, nullptr, nullptr, nullptr, N, 128);
        // mid = gelu(h@Wmid + bmid) -> bf16 N x 256
        mfma_gemm<128, true, false, false><<<dim3(2, GB), 256, 0, stream>>>(
            ab, wmidf + l * 32768, bmid + l * 256, nullptr, nullptr, nullptr,
            nullptr, midb, nullptr, nullptr, nullptr, nullptr, N, 256);
        // x = LN2(mid@Wo + bo + h); last layer: fused pooled readout
        if (l < NLAYER - 1) {
            mfma_gemm<256, false, true, false><<<dim3(1, GB), 256, 0, stream>>>(
                midb, wof + l * 32768, bo + l * 128, h, ln2g + l * 128, ln2b + l * 128,
                x, xb, nullptr, nullptr, nullptr, nullptr, N, 128);
        } else {
            mfma_gemm<256, false, true, true><<<dim3(1, GB), 256, 0, stream>>>(
                midb, wof + l * 32768, bo + l * 128, h, ln2g + l * 128, ln2b + l * 128,
                nullptr, nullptr, batch_idx, invc, Wout, out, N, 128);
        }
    }
}